// Round 6
// baseline (547.767 us; speedup 1.0000x reference)
//
#include <hip/hip_runtime.h>
#include <hip/hip_bf16.h>
#include <stdint.h>

// MultiheadAttention (T=512, B=32, H=16, hd=64, D=1024); bmm batched over the
// sequence dim. Pipeline: convw -> merged 3x proj GEMM (fp32 A staged+converted,
// B via global_load_lds, XCD band-affinity swizzle) -> fused attn (SINGLE-pass:
// QK^T+exp+pack-to-bf16-regs once, unnormalized; w via DPP allreduce; PV with
// shfl'd inv post-scale; 2x16KB K/V^T LDS slot ring) -> out GEMM. ws: 104 MiB.

typedef __attribute__((ext_vector_type(8))) short bf16x8;
typedef __attribute__((ext_vector_type(4))) float f32x4;
typedef unsigned short u16;
typedef unsigned int u32;

typedef __attribute__((address_space(1))) const unsigned int as1_u32;
typedef __attribute__((address_space(3))) unsigned int as3_u32;

__device__ __forceinline__ void glds16(const void* g, void* l) {
    __builtin_amdgcn_global_load_lds((as1_u32*)g, (as3_u32*)l, 16, 0, 0);
}

__device__ __forceinline__ u16 f2bf(float f) {
    u32 u = __builtin_bit_cast(u32, f);
    u32 r = (u + 0x7FFFu + ((u >> 16) & 1u)) >> 16;
    return (u16)r;
}

__device__ __forceinline__ bf16x8 pk8(float4 a, float4 b) {
    union { bf16x8 v; u16 h[8]; } o;
    o.h[0] = f2bf(a.x); o.h[1] = f2bf(a.y); o.h[2] = f2bf(a.z); o.h[3] = f2bf(a.w);
    o.h[4] = f2bf(b.x); o.h[5] = f2bf(b.y); o.h[6] = f2bf(b.z); o.h[7] = f2bf(b.w);
    return o.v;
}

template <int CTRL>
__device__ __forceinline__ float dpp_add(float x) {
    int xi = __builtin_bit_cast(int, x);
    int yi = __builtin_amdgcn_update_dpp(0, xi, CTRL, 0xF, 0xF, true);
    return x + __builtin_bit_cast(float, yi);
}
__device__ __forceinline__ float red16(float v) {
    v = dpp_add<0xB1>(v);    // quad_perm [1,0,3,2]
    v = dpp_add<0x4E>(v);    // quad_perm [2,3,0,1]
    v = dpp_add<0x141>(v);   // row_half_mirror (i^7)
    v = dpp_add<0x140>(v);   // row_mirror (i^15)
    return v;
}

// ------------------------------------------------ weights fp32 -> bf16 ----
__global__ void convw_kernel(const float4* __restrict__ Wq, const float4* __restrict__ Wk,
                             const float4* __restrict__ Wv, const float4* __restrict__ Wo,
                             uint2* __restrict__ wqb, uint2* __restrict__ wkb,
                             uint2* __restrict__ wvb, uint2* __restrict__ wob) {
    const int NT = gridDim.x * blockDim.x;
    for (int i = blockIdx.x * blockDim.x + threadIdx.x; i < 1048576; i += NT) {
        int wsel = i >> 18, di = i & 262143;
        const float4* s = wsel == 0 ? Wq : wsel == 1 ? Wk : wsel == 2 ? Wv : Wo;
        uint2* d = wsel == 0 ? wqb : wsel == 1 ? wkb : wsel == 2 ? wvb : wob;
        float4 v = s[di];
        uint2 r;
        r.x = (u32)f2bf(v.x) | ((u32)f2bf(v.y) << 16);
        r.y = (u32)f2bf(v.z) | ((u32)f2bf(v.w) << 16);
        d[di] = r;
    }
}

// ----------------------------------------------------- merged proj GEMM ----
__global__ __launch_bounds__(256, 2)
void gemm3_kernel(const float* __restrict__ Aq, const float* __restrict__ Ak,
                  const float* __restrict__ Av,
                  const u16* __restrict__ Bq, const u16* __restrict__ Bk,
                  const u16* __restrict__ Bv,
                  const float* __restrict__ bq, const float* __restrict__ bk,
                  const float* __restrict__ bv,
                  u16* __restrict__ Cq, u16* __restrict__ Ck, u16* __restrict__ Cv) {
    __shared__ __align__(16) u16 As[8192];
    __shared__ __align__(16) u16 Bs[2][8192];
    const int z = blockIdx.z;
    const float* A = z == 0 ? Aq : z == 1 ? Ak : Av;
    const u16* B = z == 0 ? Bq : z == 1 ? Bk : Bv;
    const float* bias = z == 0 ? bq : z == 1 ? bk : bv;
    u16* C = z == 0 ? Cq : z == 1 ? Ck : Cv;
    const bool qremap = (z == 0);
    const int tid = threadIdx.x;
    const int id = blockIdx.x;
    const int xcd = id & 7, j = id >> 3;
    const int ny = j & 7, band = xcd * 16 + (j >> 3);
    const long N0 = (long)ny * 128;
    const long M0 = (long)band * 128;
    const int lane = tid & 63, wv = tid >> 6;
    const int l15 = lane & 15, g = lane >> 4;
    const int wm = (wv >> 1) * 64, wn = (wv & 1) * 64;

    bf16x8 stA[4];
    auto loadA = [&](int kt) {
#pragma unroll
        for (int i2 = 0; i2 < 4; ++i2) {
            int q = tid + 256 * i2; int r = q >> 3, c16 = q & 7;
            long m = M0 + r;
            long row = qremap ? ((m & 31) * 512 + (m >> 5)) : m;
            const float* ap = A + row * 1024 + kt * 64 + c16 * 8;
            float4 f0 = *(const float4*)ap;
            float4 f1 = *(const float4*)(ap + 4);
            stA[i2] = pk8(f0, f1);
        }
    };
    auto writeA = [&]() {
#pragma unroll
        for (int i2 = 0; i2 < 4; ++i2) {
            int q = tid + 256 * i2; int r = q >> 3, c16 = q & 7;
            int d = r * 128 + ((c16 * 16) ^ ((r & 7) << 4));
            *(bf16x8*)((char*)As + d) = stA[i2];
        }
    };
    auto gldsB = [&](int kt, int buf) {
#pragma unroll
        for (int i2 = 0; i2 < 4; ++i2) {
            int q = tid + 256 * i2; int r = q >> 3, c16 = q & 7;
            int c16s = c16 ^ (r & 7);
            char* ldsbase = (char*)Bs[buf] + (i2 * 256 + wv * 64) * 16;
            glds16(B + (N0 + r) * 1024 + kt * 64 + c16s * 8, ldsbase);
        }
    };
    gldsB(0, 0);
    loadA(0);
    writeA();
    __syncthreads();
    f32x4 acc[4][4] = {};
    const int swz = (l15 & 7) << 4;
    for (int kt = 0; kt < 16; ++kt) {
        if (kt < 15) { gldsB(kt + 1, (kt + 1) & 1); loadA(kt + 1); }
        const char* Bcur = (const char*)Bs[kt & 1];
#pragma unroll
        for (int kk = 0; kk < 2; ++kk) {
            bf16x8 av[4], bvv[4];
#pragma unroll
            for (int mt = 0; mt < 4; ++mt) {
                int row = wm + mt * 16 + l15;
                av[mt] = *(const bf16x8*)((const char*)As + row * 128 + ((kk * 64 + g * 16) ^ swz));
            }
#pragma unroll
            for (int nt = 0; nt < 4; ++nt) {
                int row = wn + nt * 16 + l15;
                bvv[nt] = *(const bf16x8*)(Bcur + row * 128 + ((kk * 64 + g * 16) ^ swz));
            }
#pragma unroll
            for (int mt = 0; mt < 4; ++mt)
#pragma unroll
                for (int nt = 0; nt < 4; ++nt)
                    acc[mt][nt] = __builtin_amdgcn_mfma_f32_16x16x32_bf16(av[mt], bvv[nt], acc[mt][nt], 0, 0, 0);
        }
        __syncthreads();
        if (kt < 15) { writeA(); __syncthreads(); }
    }
    float bsv[4];
#pragma unroll
    for (int nt = 0; nt < 4; ++nt) bsv[nt] = bias[N0 + wn + nt * 16 + l15];
#pragma unroll
    for (int mt = 0; mt < 4; ++mt)
#pragma unroll
        for (int nt = 0; nt < 4; ++nt)
#pragma unroll
            for (int r = 0; r < 4; ++r) {
                long m = M0 + wm + mt * 16 + g * 4 + r;
                long n = N0 + wn + nt * 16 + l15;
                C[m * 1024 + n] = f2bf(acc[mt][nt][r] + bsv[nt]);
            }
}

// --------------------------------------------------------------- out GEMM ----
__global__ __launch_bounds__(256, 2)
void gemm_out_kernel(const u16* __restrict__ A, const u16* __restrict__ B,
                     const float* __restrict__ bias, float* __restrict__ C) {
    __shared__ __align__(16) u16 As[2][8192];
    __shared__ __align__(16) u16 Bs[2][8192];
    const int tid = threadIdx.x;
    const int id = blockIdx.x;
    const int xcd = id & 7, j = id >> 3;
    const int ny = j & 7, band = xcd * 16 + (j >> 3);
    const long N0 = (long)ny * 128;
    const long M0 = (long)band * 128;
    const int lane = tid & 63, wv = tid >> 6;
    const int l15 = lane & 15, g = lane >> 4;
    const int wm = (wv >> 1) * 64, wn = (wv & 1) * 64;

    auto gldsAB = [&](int kt, int buf) {
#pragma unroll
        for (int i2 = 0; i2 < 4; ++i2) {
            int q = tid + 256 * i2; int r = q >> 3, c16 = q & 7;
            int c16s = c16 ^ (r & 7);
            char* lbA = (char*)As[buf] + (i2 * 256 + wv * 64) * 16;
            char* lbB = (char*)Bs[buf] + (i2 * 256 + wv * 64) * 16;
            glds16(A + (M0 + r) * 1024 + kt * 64 + c16s * 8, lbA);
            glds16(B + (N0 + r) * 1024 + kt * 64 + c16s * 8, lbB);
        }
    };
    gldsAB(0, 0);
    __syncthreads();
    f32x4 acc[4][4] = {};
    const int swz = (l15 & 7) << 4;
    for (int kt = 0; kt < 16; ++kt) {
        if (kt < 15) gldsAB(kt + 1, (kt + 1) & 1);
        const char* Acur = (const char*)As[kt & 1];
        const char* Bcur = (const char*)Bs[kt & 1];
#pragma unroll
        for (int kk = 0; kk < 2; ++kk) {
            bf16x8 av[4], bvv[4];
#pragma unroll
            for (int mt = 0; mt < 4; ++mt) {
                int row = wm + mt * 16 + l15;
                av[mt] = *(const bf16x8*)(Acur + row * 128 + ((kk * 64 + g * 16) ^ swz));
            }
#pragma unroll
            for (int nt = 0; nt < 4; ++nt) {
                int row = wn + nt * 16 + l15;
                bvv[nt] = *(const bf16x8*)(Bcur + row * 128 + ((kk * 64 + g * 16) ^ swz));
            }
#pragma unroll
            for (int mt = 0; mt < 4; ++mt)
#pragma unroll
                for (int nt = 0; nt < 4; ++nt)
                    acc[mt][nt] = __builtin_amdgcn_mfma_f32_16x16x32_bf16(av[mt], bvv[nt], acc[mt][nt], 0, 0, 0);
        }
        __syncthreads();
    }
    float bsv[4];
#pragma unroll
    for (int nt = 0; nt < 4; ++nt) bsv[nt] = bias[N0 + wn + nt * 16 + l15];
#pragma unroll
    for (int mt = 0; mt < 4; ++mt)
#pragma unroll
        for (int nt = 0; nt < 4; ++nt)
#pragma unroll
            for (int r = 0; r < 4; ++r) {
                long m = M0 + wm + mt * 16 + g * 4 + r;
                long n = N0 + wn + nt * 16 + l15;
                C[m * 1024 + n] = acc[mt][nt][r] + bsv[nt];
            }
}

// ------------------------------------------------------------- fused attn ----
__global__ __launch_bounds__(512) __attribute__((amdgpu_waves_per_eu(4, 4)))
void attn_kernel(const u16* __restrict__ Q, const u16* __restrict__ K,
                 const u16* __restrict__ V, u16* __restrict__ ctx,
                 float* __restrict__ wout) {
    __shared__ __align__(16) char smem[32768];
    const int bid = blockIdx.x;
    const int wk_ = (bid & 7) * 256 + (bid >> 3);   // bijective (2048 % 8 == 0)
    const int t = wk_ >> 2, it = wk_ & 3;
    const int tid = threadIdx.x, lane = tid & 63, wv = tid >> 6;
    const int l15 = lane & 15, g = lane >> 4;
    const int swk = (l15 & 7) << 4;
    const int bb = it * 8 + wv;
    const float ksc = 0.18033688011112042f;  // log2(e)/sqrt(64)

    const u16* Kt = K + (size_t)t * 32768;
    const u16* Vt = V + (size_t)t * 32768;

    auto stageK = [&](int q, int slot) {
#pragma unroll
        for (int hh = 0; hh < 2; ++hh) {
            int idx = hh * 512 + tid;
            int sl = idx >> 3, c16 = idx & 7;
            int csw = c16 ^ (sl & 7);
            glds16(Kt + (size_t)(q * 128 + sl) * 64 + csw * 8,
                   smem + slot * 16384 + hh * 8192 + wv * 1024);
        }
    };
    bf16x8 vreg[2];
    auto loadV = [&](int q) {
#pragma unroll
        for (int hh = 0; hh < 2; ++hh) {
            int u = hh * 512 + tid;
            int sl = u >> 3, ec = u & 7;
            vreg[hh] = *(const bf16x8*)(Vt + (size_t)(q * 128 + sl) * 64 + ec * 8);
        }
    };
    auto writeV = [&](int slot) {
        char* base = smem + slot * 16384;
#pragma unroll
        for (int hh = 0; hh < 2; ++hh) {
            int u = hh * 512 + tid;
            int sl = u >> 3, ec = u & 7;
#pragma unroll
            for (int jj = 0; jj < 8; ++jj) {
                int swv = (jj ^ (ec & 3)) << 4;
                *(u16*)(base + (ec * 8 + jj) * 256 + ((sl * 2) ^ swv)) = (u16)vreg[hh][jj];
            }
        }
    };
    // PV quarter: 16 MFMA from pP[q*4+m] against V^T slot
    f32x4 pv[4];
    auto pvQuarter = [&](const char* vb, const bf16x8* pPq) {
        __builtin_amdgcn_s_setprio(1);
#pragma unroll
        for (int m = 0; m < 4; ++m) {
            bf16x8 pa = pPq[m];
#pragma unroll
            for (int nt = 0; nt < 4; ++nt) {
                int e = nt * 16 + l15;
                int esw = ((e & 7) ^ ((e >> 3) & 3)) << 4;
                const char* vrow = vb + e * 256;
                union { bf16x8 v; uint2 uu[2]; } bv;
                bv.uu[0] = *(const uint2*)(vrow + ((m * 64 + 8 * g) ^ esw));
                bv.uu[1] = *(const uint2*)(vrow + ((m * 64 + 32 + 8 * g) ^ esw));
                pv[nt] = __builtin_amdgcn_mfma_f32_16x16x32_bf16(pa, bv.v, pv[nt], 0, 0, 0);
            }
        }
        __builtin_amdgcn_s_setprio(0);
    };

    const int c = 32 * l15 + bb;
    const u16* qrow = Q + ((size_t)t * 512 + c) * 64;
    bf16x8 qb0 = *(const bf16x8*)(qrow + g * 8);
    bf16x8 qb1 = *(const bf16x8*)(qrow + 32 + g * 8);

    // ---------------- QK^T + exp + pack (single pass) ----------------
    stageK(0, 0);
    __syncthreads();
    float sum = 0.f;
    bf16x8 pP[16];
#pragma unroll
    for (int q = 0; q < 4; ++q) {
        if (q < 3) stageK(q + 1, (q + 1) & 1);
        else loadV(0);
        const char* kb = smem + (q & 1) * 16384;
        __builtin_amdgcn_s_setprio(1);
#pragma unroll
        for (int m = 0; m < 4; ++m) {
            union { bf16x8 v; u32 u[4]; } pa;
#pragma unroll
            for (int h2 = 0; h2 < 2; ++h2) {
                int lsl = 2 * m + h2;
                const char* rowp = kb + (lsl * 16 + l15) * 128;
                bf16x8 a0 = *(const bf16x8*)(rowp + ((g * 16) ^ swk));
                bf16x8 a1 = *(const bf16x8*)(rowp + ((64 + g * 16) ^ swk));
                f32x4 zz = {0.f, 0.f, 0.f, 0.f};
                zz = __builtin_amdgcn_mfma_f32_16x16x32_bf16(a0, qb0, zz, 0, 0, 0);
                zz = __builtin_amdgcn_mfma_f32_16x16x32_bf16(a1, qb1, zz, 0, 0, 0);
                float e0 = exp2f(zz[0] * ksc), e1 = exp2f(zz[1] * ksc);
                float e2 = exp2f(zz[2] * ksc), e3 = exp2f(zz[3] * ksc);
                sum += (e0 + e1) + (e2 + e3);
                pa.u[2 * h2]     = (u32)f2bf(e0) | ((u32)f2bf(e1) << 16);
                pa.u[2 * h2 + 1] = (u32)f2bf(e2) | ((u32)f2bf(e3) << 16);
            }
            pP[q * 4 + m] = pa.v;
        }
        __builtin_amdgcn_s_setprio(0);
        __syncthreads();
    }
    sum += __shfl_xor(sum, 16);
    sum += __shfl_xor(sum, 32);
    const float inv = 1.f / sum;

    // V0 -> slot0 (K fully consumed); V1 load hides under the w-phase VALU
    writeV(0);
    loadV(1);

    // ---------------- w head-mean (DPP allreduce over l15) ----------------
    {
        const float inv16 = inv * 0.0625f;
        float4 wreg0 = {0.f, 0.f, 0.f, 0.f}, wreg1 = {0.f, 0.f, 0.f, 0.f};
#pragma unroll
        for (int st = 0; st < 32; ++st) {
            union { bf16x8 v; u32 u[4]; } pu; pu.v = pP[st >> 1];
            u32 ua = pu.u[(st & 1) * 2], ub = pu.u[(st & 1) * 2 + 1];
            float v0 = __builtin_bit_cast(float, (ua & 0xFFFFu) << 16) * inv16;
            float v1 = __builtin_bit_cast(float, ua & 0xFFFF0000u) * inv16;
            float v2 = __builtin_bit_cast(float, (ub & 0xFFFFu) << 16) * inv16;
            float v3 = __builtin_bit_cast(float, ub & 0xFFFF0000u) * inv16;
            v0 = red16(v0); v1 = red16(v1); v2 = red16(v2); v3 = red16(v3);
            if ((st >> 1) == l15) {
                if (st & 1) wreg1 = (float4){v0, v1, v2, v3};
                else        wreg0 = (float4){v0, v1, v2, v3};
            }
        }
        float* wrow = wout + ((size_t)(bb * 512 + t)) * 512 + 32 * l15 + 4 * g;
        *(float4*)(wrow) = wreg0;
        *(float4*)(wrow + 16) = wreg1;
    }
    __syncthreads();   // V0 visible to all waves

    // ---------------- PV: {writeV(next), PV(cur), loadV(next+1), sync} ----------------
#pragma unroll
    for (int nt = 0; nt < 4; ++nt) pv[nt] = (f32x4){0.f, 0.f, 0.f, 0.f};
    writeV(1);                    // V1 -> slot1
    pvQuarter(smem, &pP[0]);      // V0 @ slot0
    loadV(2);
    __syncthreads();
    writeV(0);                    // V2 -> slot0
    pvQuarter(smem + 16384, &pP[4]);   // V1 @ slot1
    loadV(3);
    __syncthreads();
    writeV(1);                    // V3 -> slot1
    pvQuarter(smem, &pP[8]);      // V2 @ slot0
    __syncthreads();
    pvQuarter(smem + 16384, &pP[12]);  // V3 @ slot1

    // ctx row c' = 32*(4g+r) + bb, col e = nt*16 + l15; scale by 1/l of row c'
    float invv[4];
#pragma unroll
    for (int r = 0; r < 4; ++r) invv[r] = __shfl(inv, g * 4 + r);
#pragma unroll
    for (int nt = 0; nt < 4; ++nt)
#pragma unroll
        for (int r = 0; r < 4; ++r)
            ctx[((size_t)t * 512 + 32 * (g * 4 + r) + bb) * 64 + nt * 16 + l15] =
                f2bf(pv[nt][r] * invv[r]);
}

// ------------------------------------------------------------------ launch ----
extern "C" void kernel_launch(void* const* d_in, const int* in_sizes, int n_in,
                              void* d_out, int out_size, void* d_ws, size_t ws_size,
                              hipStream_t stream) {
    const float* query = (const float*)d_in[0];
    const float* key   = (const float*)d_in[1];
    const float* value = (const float*)d_in[2];
    const float* Wq = (const float*)d_in[3];  const float* bq = (const float*)d_in[4];
    const float* Wk = (const float*)d_in[5];  const float* bk = (const float*)d_in[6];
    const float* Wv = (const float*)d_in[7];  const float* bv = (const float*)d_in[8];
    const float* Wo = (const float*)d_in[9];  const float* bo = (const float*)d_in[10];

    char* ws = (char*)d_ws;
    u16* wqb  = (u16*)(ws + 0);
    u16* wkb  = (u16*)(ws + 2097152);
    u16* wvb  = (u16*)(ws + 4194304);
    u16* wob  = (u16*)(ws + 6291456);
    u16* q_ws = (u16*)(ws + 8388608);
    u16* k_ws = (u16*)(ws + 41943040);
    u16* v_ws = (u16*)(ws + 75497472);

    float* out  = (float*)d_out;
    float* wout = out + 16777216;

    convw_kernel<<<1024, 256, 0, stream>>>(
        (const float4*)Wq, (const float4*)Wk, (const float4*)Wv, (const float4*)Wo,
        (uint2*)wqb, (uint2*)wkb, (uint2*)wvb, (uint2*)wob);

    dim3 gg3(1024, 1, 3);
    gemm3_kernel<<<gg3, 256, 0, stream>>>(query, key, value, wqb, wkb, wvb,
                                          bq, bk, bv, q_ws, k_ws, v_ws);

    attn_kernel<<<2048, 512, 0, stream>>>(q_ws, k_ws, v_ws, q_ws, wout);

    gemm_out_kernel<<<1024, 256, 0, stream>>>(q_ws, wob, bo, out);
}

// Round 7
// 543.788 us; speedup vs baseline: 1.0073x; 1.0073x over previous
//
#include <hip/hip_runtime.h>
#include <hip/hip_bf16.h>
#include <stdint.h>

// MultiheadAttention (T=512, B=32, H=16, hd=64, D=1024); bmm batched over the
// sequence dim. Pipeline: convw -> merged 3x proj GEMM (fp32 A staged+converted,
// B via global_load_lds, XCD band-affinity swizzle) -> fused attn (SINGLE-pass:
// QK^T+exp+pack-to-bf16-regs once, unnormalized; w via DPP allreduce; PV with
// shfl'd inv post-scale; 2x16KB K/V^T LDS slot ring; P fragments passed BY VALUE
// so pP[16] stays in VGPRs) -> out GEMM. ws: 104 MiB.

typedef __attribute__((ext_vector_type(8))) short bf16x8;
typedef __attribute__((ext_vector_type(4))) float f32x4;
typedef unsigned short u16;
typedef unsigned int u32;

typedef __attribute__((address_space(1))) const unsigned int as1_u32;
typedef __attribute__((address_space(3))) unsigned int as3_u32;

__device__ __forceinline__ void glds16(const void* g, void* l) {
    __builtin_amdgcn_global_load_lds((as1_u32*)g, (as3_u32*)l, 16, 0, 0);
}

__device__ __forceinline__ u16 f2bf(float f) {
    u32 u = __builtin_bit_cast(u32, f);
    u32 r = (u + 0x7FFFu + ((u >> 16) & 1u)) >> 16;
    return (u16)r;
}

__device__ __forceinline__ bf16x8 pk8(float4 a, float4 b) {
    union { bf16x8 v; u16 h[8]; } o;
    o.h[0] = f2bf(a.x); o.h[1] = f2bf(a.y); o.h[2] = f2bf(a.z); o.h[3] = f2bf(a.w);
    o.h[4] = f2bf(b.x); o.h[5] = f2bf(b.y); o.h[6] = f2bf(b.z); o.h[7] = f2bf(b.w);
    return o.v;
}

template <int CTRL>
__device__ __forceinline__ float dpp_add(float x) {
    int xi = __builtin_bit_cast(int, x);
    int yi = __builtin_amdgcn_update_dpp(0, xi, CTRL, 0xF, 0xF, true);
    return x + __builtin_bit_cast(float, yi);
}
__device__ __forceinline__ float red16(float v) {
    v = dpp_add<0xB1>(v);    // quad_perm [1,0,3,2]
    v = dpp_add<0x4E>(v);    // quad_perm [2,3,0,1]
    v = dpp_add<0x141>(v);   // row_half_mirror (i^7)
    v = dpp_add<0x140>(v);   // row_mirror (i^15)
    return v;
}

// ------------------------------------------------ weights fp32 -> bf16 ----
__global__ void convw_kernel(const float4* __restrict__ Wq, const float4* __restrict__ Wk,
                             const float4* __restrict__ Wv, const float4* __restrict__ Wo,
                             uint2* __restrict__ wqb, uint2* __restrict__ wkb,
                             uint2* __restrict__ wvb, uint2* __restrict__ wob) {
    const int NT = gridDim.x * blockDim.x;
    for (int i = blockIdx.x * blockDim.x + threadIdx.x; i < 1048576; i += NT) {
        int wsel = i >> 18, di = i & 262143;
        const float4* s = wsel == 0 ? Wq : wsel == 1 ? Wk : wsel == 2 ? Wv : Wo;
        uint2* d = wsel == 0 ? wqb : wsel == 1 ? wkb : wsel == 2 ? wvb : wob;
        float4 v = s[di];
        uint2 r;
        r.x = (u32)f2bf(v.x) | ((u32)f2bf(v.y) << 16);
        r.y = (u32)f2bf(v.z) | ((u32)f2bf(v.w) << 16);
        d[di] = r;
    }
}

// ----------------------------------------------------- merged proj GEMM ----
__global__ __launch_bounds__(256, 2)
void gemm3_kernel(const float* __restrict__ Aq, const float* __restrict__ Ak,
                  const float* __restrict__ Av,
                  const u16* __restrict__ Bq, const u16* __restrict__ Bk,
                  const u16* __restrict__ Bv,
                  const float* __restrict__ bq, const float* __restrict__ bk,
                  const float* __restrict__ bv,
                  u16* __restrict__ Cq, u16* __restrict__ Ck, u16* __restrict__ Cv) {
    __shared__ __align__(16) u16 As[8192];
    __shared__ __align__(16) u16 Bs[2][8192];
    const int z = blockIdx.z;
    const float* A = z == 0 ? Aq : z == 1 ? Ak : Av;
    const u16* B = z == 0 ? Bq : z == 1 ? Bk : Bv;
    const float* bias = z == 0 ? bq : z == 1 ? bk : bv;
    u16* C = z == 0 ? Cq : z == 1 ? Ck : Cv;
    const bool qremap = (z == 0);
    const int tid = threadIdx.x;
    const int id = blockIdx.x;
    const int xcd = id & 7, j = id >> 3;
    const int ny = j & 7, band = xcd * 16 + (j >> 3);
    const long N0 = (long)ny * 128;
    const long M0 = (long)band * 128;
    const int lane = tid & 63, wv = tid >> 6;
    const int l15 = lane & 15, g = lane >> 4;
    const int wm = (wv >> 1) * 64, wn = (wv & 1) * 64;

    bf16x8 stA[4];
    auto loadA = [&](int kt) {
#pragma unroll
        for (int i2 = 0; i2 < 4; ++i2) {
            int q = tid + 256 * i2; int r = q >> 3, c16 = q & 7;
            long m = M0 + r;
            long row = qremap ? ((m & 31) * 512 + (m >> 5)) : m;
            const float* ap = A + row * 1024 + kt * 64 + c16 * 8;
            float4 f0 = *(const float4*)ap;
            float4 f1 = *(const float4*)(ap + 4);
            stA[i2] = pk8(f0, f1);
        }
    };
    auto writeA = [&]() {
#pragma unroll
        for (int i2 = 0; i2 < 4; ++i2) {
            int q = tid + 256 * i2; int r = q >> 3, c16 = q & 7;
            int d = r * 128 + ((c16 * 16) ^ ((r & 7) << 4));
            *(bf16x8*)((char*)As + d) = stA[i2];
        }
    };
    auto gldsB = [&](int kt, int buf) {
#pragma unroll
        for (int i2 = 0; i2 < 4; ++i2) {
            int q = tid + 256 * i2; int r = q >> 3, c16 = q & 7;
            int c16s = c16 ^ (r & 7);
            char* ldsbase = (char*)Bs[buf] + (i2 * 256 + wv * 64) * 16;
            glds16(B + (N0 + r) * 1024 + kt * 64 + c16s * 8, ldsbase);
        }
    };
    gldsB(0, 0);
    loadA(0);
    writeA();
    __syncthreads();
    f32x4 acc[4][4] = {};
    const int swz = (l15 & 7) << 4;
    for (int kt = 0; kt < 16; ++kt) {
        if (kt < 15) { gldsB(kt + 1, (kt + 1) & 1); loadA(kt + 1); }
        const char* Bcur = (const char*)Bs[kt & 1];
#pragma unroll
        for (int kk = 0; kk < 2; ++kk) {
            bf16x8 av[4], bvv[4];
#pragma unroll
            for (int mt = 0; mt < 4; ++mt) {
                int row = wm + mt * 16 + l15;
                av[mt] = *(const bf16x8*)((const char*)As + row * 128 + ((kk * 64 + g * 16) ^ swz));
            }
#pragma unroll
            for (int nt = 0; nt < 4; ++nt) {
                int row = wn + nt * 16 + l15;
                bvv[nt] = *(const bf16x8*)(Bcur + row * 128 + ((kk * 64 + g * 16) ^ swz));
            }
#pragma unroll
            for (int mt = 0; mt < 4; ++mt)
#pragma unroll
                for (int nt = 0; nt < 4; ++nt)
                    acc[mt][nt] = __builtin_amdgcn_mfma_f32_16x16x32_bf16(av[mt], bvv[nt], acc[mt][nt], 0, 0, 0);
        }
        __syncthreads();
        if (kt < 15) { writeA(); __syncthreads(); }
    }
    float bsv[4];
#pragma unroll
    for (int nt = 0; nt < 4; ++nt) bsv[nt] = bias[N0 + wn + nt * 16 + l15];
#pragma unroll
    for (int mt = 0; mt < 4; ++mt)
#pragma unroll
        for (int nt = 0; nt < 4; ++nt)
#pragma unroll
            for (int r = 0; r < 4; ++r) {
                long m = M0 + wm + mt * 16 + g * 4 + r;
                long n = N0 + wn + nt * 16 + l15;
                C[m * 1024 + n] = f2bf(acc[mt][nt][r] + bsv[nt]);
            }
}

// --------------------------------------------------------------- out GEMM ----
__global__ __launch_bounds__(256, 2)
void gemm_out_kernel(const u16* __restrict__ A, const u16* __restrict__ B,
                     const float* __restrict__ bias, float* __restrict__ C) {
    __shared__ __align__(16) u16 As[2][8192];
    __shared__ __align__(16) u16 Bs[2][8192];
    const int tid = threadIdx.x;
    const int id = blockIdx.x;
    const int xcd = id & 7, j = id >> 3;
    const int ny = j & 7, band = xcd * 16 + (j >> 3);
    const long N0 = (long)ny * 128;
    const long M0 = (long)band * 128;
    const int lane = tid & 63, wv = tid >> 6;
    const int l15 = lane & 15, g = lane >> 4;
    const int wm = (wv >> 1) * 64, wn = (wv & 1) * 64;

    auto gldsAB = [&](int kt, int buf) {
#pragma unroll
        for (int i2 = 0; i2 < 4; ++i2) {
            int q = tid + 256 * i2; int r = q >> 3, c16 = q & 7;
            int c16s = c16 ^ (r & 7);
            char* lbA = (char*)As[buf] + (i2 * 256 + wv * 64) * 16;
            char* lbB = (char*)Bs[buf] + (i2 * 256 + wv * 64) * 16;
            glds16(A + (M0 + r) * 1024 + kt * 64 + c16s * 8, lbA);
            glds16(B + (N0 + r) * 1024 + kt * 64 + c16s * 8, lbB);
        }
    };
    gldsAB(0, 0);
    __syncthreads();
    f32x4 acc[4][4] = {};
    const int swz = (l15 & 7) << 4;
    for (int kt = 0; kt < 16; ++kt) {
        if (kt < 15) gldsAB(kt + 1, (kt + 1) & 1);
        const char* Acur = (const char*)As[kt & 1];
        const char* Bcur = (const char*)Bs[kt & 1];
#pragma unroll
        for (int kk = 0; kk < 2; ++kk) {
            bf16x8 av[4], bvv[4];
#pragma unroll
            for (int mt = 0; mt < 4; ++mt) {
                int row = wm + mt * 16 + l15;
                av[mt] = *(const bf16x8*)(Acur + row * 128 + ((kk * 64 + g * 16) ^ swz));
            }
#pragma unroll
            for (int nt = 0; nt < 4; ++nt) {
                int row = wn + nt * 16 + l15;
                bvv[nt] = *(const bf16x8*)(Bcur + row * 128 + ((kk * 64 + g * 16) ^ swz));
            }
#pragma unroll
            for (int mt = 0; mt < 4; ++mt)
#pragma unroll
                for (int nt = 0; nt < 4; ++nt)
                    acc[mt][nt] = __builtin_amdgcn_mfma_f32_16x16x32_bf16(av[mt], bvv[nt], acc[mt][nt], 0, 0, 0);
        }
        __syncthreads();
    }
    float bsv[4];
#pragma unroll
    for (int nt = 0; nt < 4; ++nt) bsv[nt] = bias[N0 + wn + nt * 16 + l15];
#pragma unroll
    for (int mt = 0; mt < 4; ++mt)
#pragma unroll
        for (int nt = 0; nt < 4; ++nt)
#pragma unroll
            for (int r = 0; r < 4; ++r) {
                long m = M0 + wm + mt * 16 + g * 4 + r;
                long n = N0 + wn + nt * 16 + l15;
                C[m * 1024 + n] = acc[mt][nt][r] + bsv[nt];
            }
}

// ------------------------------------------------------------- fused attn ----
// Grid 2048: block = (t, it); 8 waves; wave owns bb = it*8+wv; cols c = 32*l15+bb.
// Single pass: QK^T -> exp -> pack UNNORMALIZED bf16 into pP[16] (all static
// indexing; fragments passed by value -> VGPR-resident). w = DPP allreduce of
// pP*inv/16. PV uses pP directly; per-row inv applied at epilogue via shfl.
__global__ __launch_bounds__(512, 4)
void attn_kernel(const u16* __restrict__ Q, const u16* __restrict__ K,
                 const u16* __restrict__ V, u16* __restrict__ ctx,
                 float* __restrict__ wout) {
    __shared__ __align__(16) char smem[32768];
    const int bid = blockIdx.x;
    const int wk_ = (bid & 7) * 256 + (bid >> 3);   // bijective (2048 % 8 == 0)
    const int t = wk_ >> 2, it = wk_ & 3;
    const int tid = threadIdx.x, lane = tid & 63, wv = tid >> 6;
    const int l15 = lane & 15, g = lane >> 4;
    const int swk = (l15 & 7) << 4;
    const int bb = it * 8 + wv;
    const float ksc = 0.18033688011112042f;  // log2(e)/sqrt(64)

    const u16* Kt = K + (size_t)t * 32768;
    const u16* Vt = V + (size_t)t * 32768;

    auto stageK = [&](int q, int slot) {
#pragma unroll
        for (int hh = 0; hh < 2; ++hh) {
            int idx = hh * 512 + tid;
            int sl = idx >> 3, c16 = idx & 7;
            int csw = c16 ^ (sl & 7);
            glds16(Kt + (size_t)(q * 128 + sl) * 64 + csw * 8,
                   smem + slot * 16384 + hh * 8192 + wv * 1024);
        }
    };
    bf16x8 vreg[2];
    auto loadV = [&](int q) {
#pragma unroll
        for (int hh = 0; hh < 2; ++hh) {
            int u = hh * 512 + tid;
            int sl = u >> 3, ec = u & 7;
            vreg[hh] = *(const bf16x8*)(Vt + (size_t)(q * 128 + sl) * 64 + ec * 8);
        }
    };
    auto writeV = [&](int slot) {
        char* base = smem + slot * 16384;
#pragma unroll
        for (int hh = 0; hh < 2; ++hh) {
            int u = hh * 512 + tid;
            int sl = u >> 3, ec = u & 7;
#pragma unroll
            for (int jj = 0; jj < 8; ++jj) {
                int swv = (jj ^ (ec & 3)) << 4;
                *(u16*)(base + (ec * 8 + jj) * 256 + ((sl * 2) ^ swv)) = (u16)vreg[hh][jj];
            }
        }
    };
    // PV quarter: 16 MFMA; P fragments BY VALUE so pP never decays to memory
    f32x4 pv[4];
    auto pvQuarter = [&](const char* vb, bf16x8 p0, bf16x8 p1, bf16x8 p2, bf16x8 p3) {
        bf16x8 pq[4] = {p0, p1, p2, p3};
        __builtin_amdgcn_s_setprio(1);
#pragma unroll
        for (int m = 0; m < 4; ++m) {
#pragma unroll
            for (int nt = 0; nt < 4; ++nt) {
                int e = nt * 16 + l15;
                int esw = ((e & 7) ^ ((e >> 3) & 3)) << 4;
                const char* vrow = vb + e * 256;
                union { bf16x8 v; uint2 uu[2]; } bv;
                bv.uu[0] = *(const uint2*)(vrow + ((m * 64 + 8 * g) ^ esw));
                bv.uu[1] = *(const uint2*)(vrow + ((m * 64 + 32 + 8 * g) ^ esw));
                pv[nt] = __builtin_amdgcn_mfma_f32_16x16x32_bf16(pq[m], bv.v, pv[nt], 0, 0, 0);
            }
        }
        __builtin_amdgcn_s_setprio(0);
    };

    const int c = 32 * l15 + bb;
    const u16* qrow = Q + ((size_t)t * 512 + c) * 64;
    bf16x8 qb0 = *(const bf16x8*)(qrow + g * 8);
    bf16x8 qb1 = *(const bf16x8*)(qrow + 32 + g * 8);

    // ---------------- QK^T + exp + pack (single pass) ----------------
    stageK(0, 0);
    __syncthreads();
    float sum = 0.f;
    bf16x8 pP[16];
#pragma unroll
    for (int q = 0; q < 4; ++q) {
        if (q < 3) stageK(q + 1, (q + 1) & 1);
        else loadV(0);
        const char* kb = smem + (q & 1) * 16384;
        __builtin_amdgcn_s_setprio(1);
#pragma unroll
        for (int m = 0; m < 4; ++m) {
            union { bf16x8 v; u32 u[4]; } pa;
#pragma unroll
            for (int h2 = 0; h2 < 2; ++h2) {
                int lsl = 2 * m + h2;
                const char* rowp = kb + (lsl * 16 + l15) * 128;
                bf16x8 a0 = *(const bf16x8*)(rowp + ((g * 16) ^ swk));
                bf16x8 a1 = *(const bf16x8*)(rowp + ((64 + g * 16) ^ swk));
                f32x4 zz = {0.f, 0.f, 0.f, 0.f};
                zz = __builtin_amdgcn_mfma_f32_16x16x32_bf16(a0, qb0, zz, 0, 0, 0);
                zz = __builtin_amdgcn_mfma_f32_16x16x32_bf16(a1, qb1, zz, 0, 0, 0);
                float e0 = exp2f(zz[0] * ksc), e1 = exp2f(zz[1] * ksc);
                float e2 = exp2f(zz[2] * ksc), e3 = exp2f(zz[3] * ksc);
                sum += (e0 + e1) + (e2 + e3);
                pa.u[2 * h2]     = (u32)f2bf(e0) | ((u32)f2bf(e1) << 16);
                pa.u[2 * h2 + 1] = (u32)f2bf(e2) | ((u32)f2bf(e3) << 16);
            }
            pP[q * 4 + m] = pa.v;
        }
        __builtin_amdgcn_s_setprio(0);
        __syncthreads();
    }
    sum += __shfl_xor(sum, 16);
    sum += __shfl_xor(sum, 32);
    const float inv = 1.f / sum;

    // V0 -> slot0 (K fully consumed); V1 load hides under the w-phase VALU
    writeV(0);
    loadV(1);

    // ---------------- w head-mean (DPP allreduce over l15) ----------------
    {
        const float inv16 = inv * 0.0625f;
        float4 wreg0 = {0.f, 0.f, 0.f, 0.f}, wreg1 = {0.f, 0.f, 0.f, 0.f};
#pragma unroll
        for (int st = 0; st < 32; ++st) {
            union { bf16x8 v; u32 u[4]; } pu; pu.v = pP[st >> 1];
            u32 ua = pu.u[(st & 1) * 2], ub = pu.u[(st & 1) * 2 + 1];
            float v0 = __builtin_bit_cast(float, (ua & 0xFFFFu) << 16) * inv16;
            float v1 = __builtin_bit_cast(float, ua & 0xFFFF0000u) * inv16;
            float v2 = __builtin_bit_cast(float, (ub & 0xFFFFu) << 16) * inv16;
            float v3 = __builtin_bit_cast(float, ub & 0xFFFF0000u) * inv16;
            v0 = red16(v0); v1 = red16(v1); v2 = red16(v2); v3 = red16(v3);
            if ((st >> 1) == l15) {
                if (st & 1) wreg1 = (float4){v0, v1, v2, v3};
                else        wreg0 = (float4){v0, v1, v2, v3};
            }
        }
        float* wrow = wout + ((size_t)(bb * 512 + t)) * 512 + 32 * l15 + 4 * g;
        *(float4*)(wrow) = wreg0;
        *(float4*)(wrow + 16) = wreg1;
    }
    __syncthreads();   // V0 visible to all waves

    // ---------------- PV: {writeV(next), PV(cur), loadV(next+1), sync} ----------------
#pragma unroll
    for (int nt = 0; nt < 4; ++nt) pv[nt] = (f32x4){0.f, 0.f, 0.f, 0.f};
    writeV(1);                                        // V1 -> slot1
    pvQuarter(smem, pP[0], pP[1], pP[2], pP[3]);      // V0 @ slot0
    loadV(2);
    __syncthreads();
    writeV(0);                                        // V2 -> slot0
    pvQuarter(smem + 16384, pP[4], pP[5], pP[6], pP[7]);   // V1 @ slot1
    loadV(3);
    __syncthreads();
    writeV(1);                                        // V3 -> slot1
    pvQuarter(smem, pP[8], pP[9], pP[10], pP[11]);    // V2 @ slot0
    __syncthreads();
    pvQuarter(smem + 16384, pP[12], pP[13], pP[14], pP[15]);  // V3 @ slot1

    // ctx row c' = 32*(4g+r) + bb, col e = nt*16 + l15; scale by 1/l of row c'
    float invv[4];
#pragma unroll
    for (int r = 0; r < 4; ++r) invv[r] = __shfl(inv, g * 4 + r);
#pragma unroll
    for (int nt = 0; nt < 4; ++nt)
#pragma unroll
        for (int r = 0; r < 4; ++r)
            ctx[((size_t)t * 512 + 32 * (g * 4 + r) + bb) * 64 + nt * 16 + l15] =
                f2bf(pv[nt][r] * invv[r]);
}

// ------------------------------------------------------------------ launch ----
extern "C" void kernel_launch(void* const* d_in, const int* in_sizes, int n_in,
                              void* d_out, int out_size, void* d_ws, size_t ws_size,
                              hipStream_t stream) {
    const float* query = (const float*)d_in[0];
    const float* key   = (const float*)d_in[1];
    const float* value = (const float*)d_in[2];
    const float* Wq = (const float*)d_in[3];  const float* bq = (const float*)d_in[4];
    const float* Wk = (const float*)d_in[5];  const float* bk = (const float*)d_in[6];
    const float* Wv = (const float*)d_in[7];  const float* bv = (const float*)d_in[8];
    const float* Wo = (const float*)d_in[9];  const float* bo = (const float*)d_in[10];

    char* ws = (char*)d_ws;
    u16* wqb  = (u16*)(ws + 0);
    u16* wkb  = (u16*)(ws + 2097152);
    u16* wvb  = (u16*)(ws + 4194304);
    u16* wob  = (u16*)(ws + 6291456);
    u16* q_ws = (u16*)(ws + 8388608);
    u16* k_ws = (u16*)(ws + 41943040);
    u16* v_ws = (u16*)(ws + 75497472);

    float* out  = (float*)d_out;
    float* wout = out + 16777216;

    convw_kernel<<<1024, 256, 0, stream>>>(
        (const float4*)Wq, (const float4*)Wk, (const float4*)Wv, (const float4*)Wo,
        (uint2*)wqb, (uint2*)wkb, (uint2*)wvb, (uint2*)wob);

    dim3 gg3(1024, 1, 3);
    gemm3_kernel<<<gg3, 256, 0, stream>>>(query, key, value, wqb, wkb, wvb,
                                          bq, bk, bv, q_ws, k_ws, v_ws);

    attn_kernel<<<2048, 512, 0, stream>>>(q_ws, k_ws, v_ws, q_ws, wout);

    gemm_out_kernel<<<1024, 256, 0, stream>>>(q_ws, wob, bo, out);
}

// Round 8
// 378.950 us; speedup vs baseline: 1.4455x; 1.4350x over previous
//
#include <hip/hip_runtime.h>
#include <hip/hip_bf16.h>
#include <stdint.h>

// MultiheadAttention (T=512, B=32, H=16, hd=64, D=1024); bmm batched over the
// sequence dim. Pipeline: convw -> merged 3x proj GEMM (fp32 A staged+converted,
// B via global_load_lds, XCD band-affinity swizzle) -> fused attn (SINGLE-pass:
// QK^T+exp+pack-to-bf16-regs once, unnormalized; w via DPP allreduce; PV with
// shfl'd inv post-scale; 2x16KB K/V^T LDS slot ring). launch_bounds(512,2):
// with 8-wave blocks the 2nd arg acts as blocks/CU -> 2 blocks = 128-VGPR cap,
// which fits the ~110-reg live set WITHOUT spilling pP (the (512,4) build
// capped at 64 VGPR and spilled 1.1 GB/dispatch of scratch). -> out GEMM.

typedef __attribute__((ext_vector_type(8))) short bf16x8;
typedef __attribute__((ext_vector_type(4))) float f32x4;
typedef unsigned short u16;
typedef unsigned int u32;

typedef __attribute__((address_space(1))) const unsigned int as1_u32;
typedef __attribute__((address_space(3))) unsigned int as3_u32;

__device__ __forceinline__ void glds16(const void* g, void* l) {
    __builtin_amdgcn_global_load_lds((as1_u32*)g, (as3_u32*)l, 16, 0, 0);
}

__device__ __forceinline__ u16 f2bf(float f) {
    u32 u = __builtin_bit_cast(u32, f);
    u32 r = (u + 0x7FFFu + ((u >> 16) & 1u)) >> 16;
    return (u16)r;
}

__device__ __forceinline__ bf16x8 pk8(float4 a, float4 b) {
    union { bf16x8 v; u16 h[8]; } o;
    o.h[0] = f2bf(a.x); o.h[1] = f2bf(a.y); o.h[2] = f2bf(a.z); o.h[3] = f2bf(a.w);
    o.h[4] = f2bf(b.x); o.h[5] = f2bf(b.y); o.h[6] = f2bf(b.z); o.h[7] = f2bf(b.w);
    return o.v;
}

template <int CTRL>
__device__ __forceinline__ float dpp_add(float x) {
    int xi = __builtin_bit_cast(int, x);
    int yi = __builtin_amdgcn_update_dpp(0, xi, CTRL, 0xF, 0xF, true);
    return x + __builtin_bit_cast(float, yi);
}
__device__ __forceinline__ float red16(float v) {
    v = dpp_add<0xB1>(v);    // quad_perm [1,0,3,2]
    v = dpp_add<0x4E>(v);    // quad_perm [2,3,0,1]
    v = dpp_add<0x141>(v);   // row_half_mirror (i^7)
    v = dpp_add<0x140>(v);   // row_mirror (i^15)
    return v;
}

// ------------------------------------------------ weights fp32 -> bf16 ----
__global__ void convw_kernel(const float4* __restrict__ Wq, const float4* __restrict__ Wk,
                             const float4* __restrict__ Wv, const float4* __restrict__ Wo,
                             uint2* __restrict__ wqb, uint2* __restrict__ wkb,
                             uint2* __restrict__ wvb, uint2* __restrict__ wob) {
    const int NT = gridDim.x * blockDim.x;
    for (int i = blockIdx.x * blockDim.x + threadIdx.x; i < 1048576; i += NT) {
        int wsel = i >> 18, di = i & 262143;
        const float4* s = wsel == 0 ? Wq : wsel == 1 ? Wk : wsel == 2 ? Wv : Wo;
        uint2* d = wsel == 0 ? wqb : wsel == 1 ? wkb : wsel == 2 ? wvb : wob;
        float4 v = s[di];
        uint2 r;
        r.x = (u32)f2bf(v.x) | ((u32)f2bf(v.y) << 16);
        r.y = (u32)f2bf(v.z) | ((u32)f2bf(v.w) << 16);
        d[di] = r;
    }
}

// ----------------------------------------------------- merged proj GEMM ----
__global__ __launch_bounds__(256, 2)
void gemm3_kernel(const float* __restrict__ Aq, const float* __restrict__ Ak,
                  const float* __restrict__ Av,
                  const u16* __restrict__ Bq, const u16* __restrict__ Bk,
                  const u16* __restrict__ Bv,
                  const float* __restrict__ bq, const float* __restrict__ bk,
                  const float* __restrict__ bv,
                  u16* __restrict__ Cq, u16* __restrict__ Ck, u16* __restrict__ Cv) {
    __shared__ __align__(16) u16 As[8192];
    __shared__ __align__(16) u16 Bs[2][8192];
    const int z = blockIdx.z;
    const float* A = z == 0 ? Aq : z == 1 ? Ak : Av;
    const u16* B = z == 0 ? Bq : z == 1 ? Bk : Bv;
    const float* bias = z == 0 ? bq : z == 1 ? bk : bv;
    u16* C = z == 0 ? Cq : z == 1 ? Ck : Cv;
    const bool qremap = (z == 0);
    const int tid = threadIdx.x;
    const int id = blockIdx.x;
    const int xcd = id & 7, j = id >> 3;
    const int ny = j & 7, band = xcd * 16 + (j >> 3);
    const long N0 = (long)ny * 128;
    const long M0 = (long)band * 128;
    const int lane = tid & 63, wv = tid >> 6;
    const int l15 = lane & 15, g = lane >> 4;
    const int wm = (wv >> 1) * 64, wn = (wv & 1) * 64;

    bf16x8 stA[4];
    auto loadA = [&](int kt) {
#pragma unroll
        for (int i2 = 0; i2 < 4; ++i2) {
            int q = tid + 256 * i2; int r = q >> 3, c16 = q & 7;
            long m = M0 + r;
            long row = qremap ? ((m & 31) * 512 + (m >> 5)) : m;
            const float* ap = A + row * 1024 + kt * 64 + c16 * 8;
            float4 f0 = *(const float4*)ap;
            float4 f1 = *(const float4*)(ap + 4);
            stA[i2] = pk8(f0, f1);
        }
    };
    auto writeA = [&]() {
#pragma unroll
        for (int i2 = 0; i2 < 4; ++i2) {
            int q = tid + 256 * i2; int r = q >> 3, c16 = q & 7;
            int d = r * 128 + ((c16 * 16) ^ ((r & 7) << 4));
            *(bf16x8*)((char*)As + d) = stA[i2];
        }
    };
    auto gldsB = [&](int kt, int buf) {
#pragma unroll
        for (int i2 = 0; i2 < 4; ++i2) {
            int q = tid + 256 * i2; int r = q >> 3, c16 = q & 7;
            int c16s = c16 ^ (r & 7);
            char* ldsbase = (char*)Bs[buf] + (i2 * 256 + wv * 64) * 16;
            glds16(B + (N0 + r) * 1024 + kt * 64 + c16s * 8, ldsbase);
        }
    };
    gldsB(0, 0);
    loadA(0);
    writeA();
    __syncthreads();
    f32x4 acc[4][4] = {};
    const int swz = (l15 & 7) << 4;
    for (int kt = 0; kt < 16; ++kt) {
        if (kt < 15) { gldsB(kt + 1, (kt + 1) & 1); loadA(kt + 1); }
        const char* Bcur = (const char*)Bs[kt & 1];
#pragma unroll
        for (int kk = 0; kk < 2; ++kk) {
            bf16x8 av[4], bvv[4];
#pragma unroll
            for (int mt = 0; mt < 4; ++mt) {
                int row = wm + mt * 16 + l15;
                av[mt] = *(const bf16x8*)((const char*)As + row * 128 + ((kk * 64 + g * 16) ^ swz));
            }
#pragma unroll
            for (int nt = 0; nt < 4; ++nt) {
                int row = wn + nt * 16 + l15;
                bvv[nt] = *(const bf16x8*)(Bcur + row * 128 + ((kk * 64 + g * 16) ^ swz));
            }
#pragma unroll
            for (int mt = 0; mt < 4; ++mt)
#pragma unroll
                for (int nt = 0; nt < 4; ++nt)
                    acc[mt][nt] = __builtin_amdgcn_mfma_f32_16x16x32_bf16(av[mt], bvv[nt], acc[mt][nt], 0, 0, 0);
        }
        __syncthreads();
        if (kt < 15) { writeA(); __syncthreads(); }
    }
    float bsv[4];
#pragma unroll
    for (int nt = 0; nt < 4; ++nt) bsv[nt] = bias[N0 + wn + nt * 16 + l15];
#pragma unroll
    for (int mt = 0; mt < 4; ++mt)
#pragma unroll
        for (int nt = 0; nt < 4; ++nt)
#pragma unroll
            for (int r = 0; r < 4; ++r) {
                long m = M0 + wm + mt * 16 + g * 4 + r;
                long n = N0 + wn + nt * 16 + l15;
                C[m * 1024 + n] = f2bf(acc[mt][nt][r] + bsv[nt]);
            }
}

// --------------------------------------------------------------- out GEMM ----
__global__ __launch_bounds__(256, 2)
void gemm_out_kernel(const u16* __restrict__ A, const u16* __restrict__ B,
                     const float* __restrict__ bias, float* __restrict__ C) {
    __shared__ __align__(16) u16 As[2][8192];
    __shared__ __align__(16) u16 Bs[2][8192];
    const int tid = threadIdx.x;
    const int id = blockIdx.x;
    const int xcd = id & 7, j = id >> 3;
    const int ny = j & 7, band = xcd * 16 + (j >> 3);
    const long N0 = (long)ny * 128;
    const long M0 = (long)band * 128;
    const int lane = tid & 63, wv = tid >> 6;
    const int l15 = lane & 15, g = lane >> 4;
    const int wm = (wv >> 1) * 64, wn = (wv & 1) * 64;

    auto gldsAB = [&](int kt, int buf) {
#pragma unroll
        for (int i2 = 0; i2 < 4; ++i2) {
            int q = tid + 256 * i2; int r = q >> 3, c16 = q & 7;
            int c16s = c16 ^ (r & 7);
            char* lbA = (char*)As[buf] + (i2 * 256 + wv * 64) * 16;
            char* lbB = (char*)Bs[buf] + (i2 * 256 + wv * 64) * 16;
            glds16(A + (M0 + r) * 1024 + kt * 64 + c16s * 8, lbA);
            glds16(B + (N0 + r) * 1024 + kt * 64 + c16s * 8, lbB);
        }
    };
    gldsAB(0, 0);
    __syncthreads();
    f32x4 acc[4][4] = {};
    const int swz = (l15 & 7) << 4;
    for (int kt = 0; kt < 16; ++kt) {
        if (kt < 15) gldsAB(kt + 1, (kt + 1) & 1);
        const char* Acur = (const char*)As[kt & 1];
        const char* Bcur = (const char*)Bs[kt & 1];
#pragma unroll
        for (int kk = 0; kk < 2; ++kk) {
            bf16x8 av[4], bvv[4];
#pragma unroll
            for (int mt = 0; mt < 4; ++mt) {
                int row = wm + mt * 16 + l15;
                av[mt] = *(const bf16x8*)(Acur + row * 128 + ((kk * 64 + g * 16) ^ swz));
            }
#pragma unroll
            for (int nt = 0; nt < 4; ++nt) {
                int row = wn + nt * 16 + l15;
                bvv[nt] = *(const bf16x8*)(Bcur + row * 128 + ((kk * 64 + g * 16) ^ swz));
            }
#pragma unroll
            for (int mt = 0; mt < 4; ++mt)
#pragma unroll
                for (int nt = 0; nt < 4; ++nt)
                    acc[mt][nt] = __builtin_amdgcn_mfma_f32_16x16x32_bf16(av[mt], bvv[nt], acc[mt][nt], 0, 0, 0);
        }
        __syncthreads();
    }
    float bsv[4];
#pragma unroll
    for (int nt = 0; nt < 4; ++nt) bsv[nt] = bias[N0 + wn + nt * 16 + l15];
#pragma unroll
    for (int mt = 0; mt < 4; ++mt)
#pragma unroll
        for (int nt = 0; nt < 4; ++nt)
#pragma unroll
            for (int r = 0; r < 4; ++r) {
                long m = M0 + wm + mt * 16 + g * 4 + r;
                long n = N0 + wn + nt * 16 + l15;
                C[m * 1024 + n] = acc[mt][nt][r] + bsv[nt];
            }
}

// ------------------------------------------------------------- fused attn ----
// Grid 2048: block = (t, it); 8 waves; wave owns bb = it*8+wv; cols c = 32*l15+bb.
// Single pass: QK^T -> exp -> pack UNNORMALIZED bf16 into pP[16] (static idx).
// w = DPP allreduce of pP*inv/16 (inv applied BEFORE reduce: per-column denom).
// PV uses pP directly; per-row inv applied at epilogue via shfl.
__global__ __launch_bounds__(512, 2)
void attn_kernel(const u16* __restrict__ Q, const u16* __restrict__ K,
                 const u16* __restrict__ V, u16* __restrict__ ctx,
                 float* __restrict__ wout) {
    __shared__ __align__(16) char smem[32768];
    const int bid = blockIdx.x;
    const int wk_ = (bid & 7) * 256 + (bid >> 3);   // bijective (2048 % 8 == 0)
    const int t = wk_ >> 2, it = wk_ & 3;
    const int tid = threadIdx.x, lane = tid & 63, wv = tid >> 6;
    const int l15 = lane & 15, g = lane >> 4;
    const int swk = (l15 & 7) << 4;
    const int bb = it * 8 + wv;
    const float ksc = 0.18033688011112042f;  // log2(e)/sqrt(64)

    const u16* Kt = K + (size_t)t * 32768;
    const u16* Vt = V + (size_t)t * 32768;

    auto stageK = [&](int q, int slot) {
#pragma unroll
        for (int hh = 0; hh < 2; ++hh) {
            int idx = hh * 512 + tid;
            int sl = idx >> 3, c16 = idx & 7;
            int csw = c16 ^ (sl & 7);
            glds16(Kt + (size_t)(q * 128 + sl) * 64 + csw * 8,
                   smem + slot * 16384 + hh * 8192 + wv * 1024);
        }
    };
    bf16x8 vreg[2];
    auto loadV = [&](int q) {
#pragma unroll
        for (int hh = 0; hh < 2; ++hh) {
            int u = hh * 512 + tid;
            int sl = u >> 3, ec = u & 7;
            vreg[hh] = *(const bf16x8*)(Vt + (size_t)(q * 128 + sl) * 64 + ec * 8);
        }
    };
    auto writeV = [&](int slot) {
        char* base = smem + slot * 16384;
#pragma unroll
        for (int hh = 0; hh < 2; ++hh) {
            int u = hh * 512 + tid;
            int sl = u >> 3, ec = u & 7;
#pragma unroll
            for (int jj = 0; jj < 8; ++jj) {
                int swv = (jj ^ (ec & 3)) << 4;
                *(u16*)(base + (ec * 8 + jj) * 256 + ((sl * 2) ^ swv)) = (u16)vreg[hh][jj];
            }
        }
    };
    // PV quarter: 16 MFMA; P fragments BY VALUE so pP never decays to memory
    f32x4 pv[4];
    auto pvQuarter = [&](const char* vb, bf16x8 p0, bf16x8 p1, bf16x8 p2, bf16x8 p3) {
        bf16x8 pq[4] = {p0, p1, p2, p3};
        __builtin_amdgcn_s_setprio(1);
#pragma unroll
        for (int m = 0; m < 4; ++m) {
#pragma unroll
            for (int nt = 0; nt < 4; ++nt) {
                int e = nt * 16 + l15;
                int esw = ((e & 7) ^ ((e >> 3) & 3)) << 4;
                const char* vrow = vb + e * 256;
                union { bf16x8 v; uint2 uu[2]; } bv;
                bv.uu[0] = *(const uint2*)(vrow + ((m * 64 + 8 * g) ^ esw));
                bv.uu[1] = *(const uint2*)(vrow + ((m * 64 + 32 + 8 * g) ^ esw));
                pv[nt] = __builtin_amdgcn_mfma_f32_16x16x32_bf16(pq[m], bv.v, pv[nt], 0, 0, 0);
            }
        }
        __builtin_amdgcn_s_setprio(0);
    };

    const int c = 32 * l15 + bb;
    const u16* qrow = Q + ((size_t)t * 512 + c) * 64;
    bf16x8 qb0 = *(const bf16x8*)(qrow + g * 8);
    bf16x8 qb1 = *(const bf16x8*)(qrow + 32 + g * 8);

    // ---------------- QK^T + exp + pack (single pass) ----------------
    stageK(0, 0);
    __syncthreads();
    float sum = 0.f;
    bf16x8 pP[16];
#pragma unroll
    for (int q = 0; q < 4; ++q) {
        if (q < 3) stageK(q + 1, (q + 1) & 1);
        else loadV(0);
        const char* kb = smem + (q & 1) * 16384;
        __builtin_amdgcn_s_setprio(1);
#pragma unroll
        for (int m = 0; m < 4; ++m) {
            union { bf16x8 v; u32 u[4]; } pa;
#pragma unroll
            for (int h2 = 0; h2 < 2; ++h2) {
                int lsl = 2 * m + h2;
                const char* rowp = kb + (lsl * 16 + l15) * 128;
                bf16x8 a0 = *(const bf16x8*)(rowp + ((g * 16) ^ swk));
                bf16x8 a1 = *(const bf16x8*)(rowp + ((64 + g * 16) ^ swk));
                f32x4 zz = {0.f, 0.f, 0.f, 0.f};
                zz = __builtin_amdgcn_mfma_f32_16x16x32_bf16(a0, qb0, zz, 0, 0, 0);
                zz = __builtin_amdgcn_mfma_f32_16x16x32_bf16(a1, qb1, zz, 0, 0, 0);
                float e0 = exp2f(zz[0] * ksc), e1 = exp2f(zz[1] * ksc);
                float e2 = exp2f(zz[2] * ksc), e3 = exp2f(zz[3] * ksc);
                sum += (e0 + e1) + (e2 + e3);
                pa.u[2 * h2]     = (u32)f2bf(e0) | ((u32)f2bf(e1) << 16);
                pa.u[2 * h2 + 1] = (u32)f2bf(e2) | ((u32)f2bf(e3) << 16);
            }
            pP[q * 4 + m] = pa.v;
        }
        __builtin_amdgcn_s_setprio(0);
        __syncthreads();
    }
    sum += __shfl_xor(sum, 16);
    sum += __shfl_xor(sum, 32);
    const float inv = 1.f / sum;

    // V0 -> slot0 (K fully consumed); V1 load hides under the w-phase VALU
    writeV(0);
    loadV(1);

    // ---------------- w head-mean (DPP allreduce over l15) ----------------
    {
        const float inv16 = inv * 0.0625f;
        float4 wreg0 = {0.f, 0.f, 0.f, 0.f}, wreg1 = {0.f, 0.f, 0.f, 0.f};
#pragma unroll
        for (int st = 0; st < 32; ++st) {
            union { bf16x8 v; u32 u[4]; } pu; pu.v = pP[st >> 1];
            u32 ua = pu.u[(st & 1) * 2], ub = pu.u[(st & 1) * 2 + 1];
            float v0 = __builtin_bit_cast(float, (ua & 0xFFFFu) << 16) * inv16;
            float v1 = __builtin_bit_cast(float, ua & 0xFFFF0000u) * inv16;
            float v2 = __builtin_bit_cast(float, (ub & 0xFFFFu) << 16) * inv16;
            float v3 = __builtin_bit_cast(float, ub & 0xFFFF0000u) * inv16;
            v0 = red16(v0); v1 = red16(v1); v2 = red16(v2); v3 = red16(v3);
            if ((st >> 1) == l15) {
                if (st & 1) wreg1 = (float4){v0, v1, v2, v3};
                else        wreg0 = (float4){v0, v1, v2, v3};
            }
        }
        float* wrow = wout + ((size_t)(bb * 512 + t)) * 512 + 32 * l15 + 4 * g;
        *(float4*)(wrow) = wreg0;
        *(float4*)(wrow + 16) = wreg1;
    }
    __syncthreads();   // V0 visible to all waves

    // ---------------- PV: {writeV(next), PV(cur), loadV(next+1), sync} ----------------
#pragma unroll
    for (int nt = 0; nt < 4; ++nt) pv[nt] = (f32x4){0.f, 0.f, 0.f, 0.f};
    writeV(1);                                        // V1 -> slot1
    pvQuarter(smem, pP[0], pP[1], pP[2], pP[3]);      // V0 @ slot0
    loadV(2);
    __syncthreads();
    writeV(0);                                        // V2 -> slot0
    pvQuarter(smem + 16384, pP[4], pP[5], pP[6], pP[7]);   // V1 @ slot1
    loadV(3);
    __syncthreads();
    writeV(1);                                        // V3 -> slot1
    pvQuarter(smem, pP[8], pP[9], pP[10], pP[11]);    // V2 @ slot0
    __syncthreads();
    pvQuarter(smem + 16384, pP[12], pP[13], pP[14], pP[15]);  // V3 @ slot1

    // ctx row c' = 32*(4g+r) + bb, col e = nt*16 + l15; scale by 1/l of row c'
    float invv[4];
#pragma unroll
    for (int r = 0; r < 4; ++r) invv[r] = __shfl(inv, g * 4 + r);
#pragma unroll
    for (int nt = 0; nt < 4; ++nt)
#pragma unroll
        for (int r = 0; r < 4; ++r)
            ctx[((size_t)t * 512 + 32 * (g * 4 + r) + bb) * 64 + nt * 16 + l15] =
                f2bf(pv[nt][r] * invv[r]);
}

// ------------------------------------------------------------------ launch ----
extern "C" void kernel_launch(void* const* d_in, const int* in_sizes, int n_in,
                              void* d_out, int out_size, void* d_ws, size_t ws_size,
                              hipStream_t stream) {
    const float* query = (const float*)d_in[0];
    const float* key   = (const float*)d_in[1];
    const float* value = (const float*)d_in[2];
    const float* Wq = (const float*)d_in[3];  const float* bq = (const float*)d_in[4];
    const float* Wk = (const float*)d_in[5];  const float* bk = (const float*)d_in[6];
    const float* Wv = (const float*)d_in[7];  const float* bv = (const float*)d_in[8];
    const float* Wo = (const float*)d_in[9];  const float* bo = (const float*)d_in[10];

    char* ws = (char*)d_ws;
    u16* wqb  = (u16*)(ws + 0);
    u16* wkb  = (u16*)(ws + 2097152);
    u16* wvb  = (u16*)(ws + 4194304);
    u16* wob  = (u16*)(ws + 6291456);
    u16* q_ws = (u16*)(ws + 8388608);
    u16* k_ws = (u16*)(ws + 41943040);
    u16* v_ws = (u16*)(ws + 75497472);

    float* out  = (float*)d_out;
    float* wout = out + 16777216;

    convw_kernel<<<1024, 256, 0, stream>>>(
        (const float4*)Wq, (const float4*)Wk, (const float4*)Wv, (const float4*)Wo,
        (uint2*)wqb, (uint2*)wkb, (uint2*)wvb, (uint2*)wob);

    dim3 gg3(1024, 1, 3);
    gemm3_kernel<<<gg3, 256, 0, stream>>>(query, key, value, wqb, wkb, wvb,
                                          bq, bk, bv, q_ws, k_ws, v_ws);

    attn_kernel<<<2048, 512, 0, stream>>>(q_ws, k_ws, v_ws, q_ws, wout);

    gemm_out_kernel<<<1024, 256, 0, stream>>>(q_ws, wob, bo, out);
}